// Round 1
// baseline (1438.575 us; speedup 1.0000x reference)
//
#include <hip/hip_runtime.h>

// ODENet forward: y' = W3^T relu(W2^T relu(W1^T y + b1) + b2) + b3, t in [0,1]
// Fixed-step RK4 (N=10 -> 40 MLP evals), f16 MFMA 16x16x32, fp32 state/accum.
// One WG (256 thr / 4 waves) per 64-row batch tile; waves partition output cols.

typedef _Float16 half8 __attribute__((ext_vector_type(8)));
typedef float floatx4 __attribute__((ext_vector_type(4)));

#define MFMA16 __builtin_amdgcn_mfma_f32_16x16x32_f16

constexpr int DDIM  = 118;   // data dim (x cols)
constexpr int NSTEP = 10;    // RK4 steps

// LDS activation buffers in MFMA A-fragment order: [rb][kc][laneSlot][j]
// element(row = 16*rb + (slot&15), k = 32*kc + 8*(slot>>4) + j)
// laneSlot is stored at physical index swz(slot) to spread write banks.
struct SMem {
  _Float16 S [4][4][64][8];   // state, K=128   16 KB
  _Float16 H1[4][8][64][8];   // hidden1, K=256 32 KB
  _Float16 H2[4][8][64][8];   // hidden2, K=256 32 KB
};
union SMemU {
  SMem a;
  float yfin[64][130];        // epilogue overlay (33 KB < 80 KB)
};

__device__ __forceinline__ int swz(int L) { return L ^ ((L >> 4) & 3); }

// Pack fp32 weight W[K][N] (row-major, k-major) into B-fragment order f16:
// out[((kc*NB + nb)*64 + L)*8 + j] = W[32*kc + 8*(L>>4) + j][16*nb + (L&15)]
__global__ void pack_weights(const float* __restrict__ W, _Float16* __restrict__ out,
                             int N, int nbShift, int total)
{
  int idx = blockIdx.x * 256 + threadIdx.x;
  if (idx >= total) return;
  int j  = idx & 7;
  int L  = (idx >> 3) & 63;
  int blk = idx >> 9;
  int nb = blk & ((1 << nbShift) - 1);
  int kc = blk >> nbShift;
  int k = 32*kc + 8*(L >> 4) + j;
  int n = 16*nb + (L & 15);
  out[idx] = (_Float16)W[k*N + n];
}

__global__ __launch_bounds__(256, 2)
void ode_kernel(const float* __restrict__ x,
                const float* __restrict__ b1v, const float* __restrict__ b2v,
                const float* __restrict__ b3v,
                const float* __restrict__ Wl,  const float* __restrict__ bl,
                const _Float16* __restrict__ Bw, float* __restrict__ out)
{
  __shared__ SMemU sm;
  const int tid = threadIdx.x;
  const int w   = tid >> 6;    // wave 0..3
  const int l   = tid & 63;    // lane
  const int q   = l >> 4;      // lane quad
  const int c   = l & 15;      // lane col
  const int lswz = swz(l);
  const int rowBase = blockIdx.x * 64;

  const _Float16* __restrict__ B1 = Bw;            // 128x256 -> 32768
  const _Float16* __restrict__ B2 = Bw + 32768;    // 256x256 -> 65536
  const _Float16* __restrict__ B3 = Bw + 98304;    // 256x128 -> 32768

  const float h = 1.0f / (float)NSTEP;

  // Per-lane biases (cols fixed for the whole kernel).
  float bs1[4], bs2[4], bs3[2];
#pragma unroll
  for (int i = 0; i < 4; ++i) {
    bs1[i] = b1v[(4*w + i)*16 + c];
    bs2[i] = b2v[(4*w + i)*16 + c];
  }
#pragma unroll
  for (int i = 0; i < 2; ++i) bs3[i] = b3v[(2*w + i)*16 + c];

  // State registers in layer-3 C-fragment layout:
  // element(row = 16*rb + 4*q + r, col = 32*w + 16*cb + c)
  float Y[4][2][4], ACC[4][2][4];
#pragma unroll
  for (int rb = 0; rb < 4; ++rb)
#pragma unroll
    for (int cb = 0; cb < 2; ++cb)
#pragma unroll
      for (int r = 0; r < 4; ++r) {
        int row = rowBase + 16*rb + 4*q + r;
        int col = 32*w + 16*cb + c;
        float v = (col < DDIM) ? x[row*DDIM + col] : 0.0f;
        Y[rb][cb][r] = v;
        ACC[rb][cb][r] = 0.0f;
        int L = 4*q + r + 16*(2*cb + (c >> 3));
        sm.a.S[rb][w][swz(L)][c & 7] = (_Float16)v;
      }

  for (int it = 0; it < 4*NSTEP; ++it) {
    const int s = it & 3;                       // RK4 stage
    __syncthreads();                            // S ready

    // ---------------- layer 1: S(64x128) @ W1(128x256) -> H1 ----------------
    floatx4 C1[4][4];
#pragma unroll
    for (int rb = 0; rb < 4; ++rb)
#pragma unroll
      for (int nbi = 0; nbi < 4; ++nbi)
#pragma unroll
        for (int r = 0; r < 4; ++r) C1[rb][nbi][r] = 0.0f;
#pragma unroll
    for (int kc = 0; kc < 4; ++kc) {
      half8 a[4];
#pragma unroll
      for (int rb = 0; rb < 4; ++rb)
        a[rb] = *(const half8*)(&sm.a.S[rb][kc][lswz][0]);
#pragma unroll
      for (int nbi = 0; nbi < 4; ++nbi) {
        const int nb = 4*w + nbi;
        half8 b = *(const half8*)(&B1[((kc*16 + nb)*64 + l)*8]);
#pragma unroll
        for (int rb = 0; rb < 4; ++rb)
          C1[rb][nbi] = MFMA16(a[rb], b, C1[rb][nbi], 0, 0, 0);
      }
    }
#pragma unroll
    for (int rb = 0; rb < 4; ++rb)
#pragma unroll
      for (int nbi = 0; nbi < 4; ++nbi) {
        const int nb  = 4*w + nbi;
        const int kcT = nb >> 1;
        const int tt  = (2*nb + (c >> 3)) & 3;
#pragma unroll
        for (int r = 0; r < 4; ++r) {
          float v = fmaxf(C1[rb][nbi][r] + bs1[nbi], 0.0f);
          int L = 4*q + r + 16*tt;
          sm.a.H1[rb][kcT][swz(L)][c & 7] = (_Float16)v;
        }
      }
    __syncthreads();                            // H1 ready

    // ---------------- layer 2: H1(64x256) @ W2(256x256) -> H2 ---------------
    floatx4 C2[4][4];
#pragma unroll
    for (int rb = 0; rb < 4; ++rb)
#pragma unroll
      for (int nbi = 0; nbi < 4; ++nbi)
#pragma unroll
        for (int r = 0; r < 4; ++r) C2[rb][nbi][r] = 0.0f;
#pragma unroll
    for (int kc = 0; kc < 8; ++kc) {
      half8 a[4];
#pragma unroll
      for (int rb = 0; rb < 4; ++rb)
        a[rb] = *(const half8*)(&sm.a.H1[rb][kc][lswz][0]);
#pragma unroll
      for (int nbi = 0; nbi < 4; ++nbi) {
        const int nb = 4*w + nbi;
        half8 b = *(const half8*)(&B2[((kc*16 + nb)*64 + l)*8]);
#pragma unroll
        for (int rb = 0; rb < 4; ++rb)
          C2[rb][nbi] = MFMA16(a[rb], b, C2[rb][nbi], 0, 0, 0);
      }
    }
#pragma unroll
    for (int rb = 0; rb < 4; ++rb)
#pragma unroll
      for (int nbi = 0; nbi < 4; ++nbi) {
        const int nb  = 4*w + nbi;
        const int kcT = nb >> 1;
        const int tt  = (2*nb + (c >> 3)) & 3;
#pragma unroll
        for (int r = 0; r < 4; ++r) {
          float v = fmaxf(C2[rb][nbi][r] + bs2[nbi], 0.0f);
          int L = 4*q + r + 16*tt;
          sm.a.H2[rb][kcT][swz(L)][c & 7] = (_Float16)v;
        }
      }
    __syncthreads();                            // H2 ready

    // ---------------- layer 3: H2(64x256) @ W3(256x128) -> k (regs) ---------
    floatx4 C3[4][2];
#pragma unroll
    for (int rb = 0; rb < 4; ++rb)
#pragma unroll
      for (int cb = 0; cb < 2; ++cb)
#pragma unroll
        for (int r = 0; r < 4; ++r) C3[rb][cb][r] = 0.0f;
#pragma unroll
    for (int kc = 0; kc < 8; ++kc) {
      half8 a[4];
#pragma unroll
      for (int rb = 0; rb < 4; ++rb)
        a[rb] = *(const half8*)(&sm.a.H2[rb][kc][lswz][0]);
#pragma unroll
      for (int cb = 0; cb < 2; ++cb) {
        const int nb = 2*w + cb;
        half8 b = *(const half8*)(&B3[((kc*8 + nb)*64 + l)*8]);
#pragma unroll
        for (int rb = 0; rb < 4; ++rb)
          C3[rb][cb] = MFMA16(a[rb], b, C3[rb][cb], 0, 0, 0);
      }
    }

    // ---------------- RK4 stage update + write next stage input -------------
    const float aw = (s == 1 || s == 2) ? 2.0f : 1.0f;
    const float cs = (s == 2) ? h : 0.5f * h;
    const bool first = (s == 0), last = (s == 3);
#pragma unroll
    for (int rb = 0; rb < 4; ++rb)
#pragma unroll
      for (int cb = 0; cb < 2; ++cb) {
        const int tt = 2*cb + (c >> 3);
#pragma unroll
        for (int r = 0; r < 4; ++r) {
          float kv = C3[rb][cb][r] + bs3[cb];
          float an = first ? kv : (ACC[rb][cb][r] + aw * kv);
          ACC[rb][cb][r] = an;
          float yv = Y[rb][cb][r];
          float ynew = yv + (h / 6.0f) * an;
          float yq = last ? ynew : yv;
          Y[rb][cb][r] = yq;
          float sn = last ? yq : (yv + cs * kv);
          int L = 4*q + r + 16*tt;
          sm.a.S[rb][w][swz(L)][c & 7] = (_Float16)sn;
        }
      }
  }

  __syncthreads();
  // Epilogue: y(1) -> LDS plain layout, then pred = y @ Wl + bl (fp32).
#pragma unroll
  for (int rb = 0; rb < 4; ++rb)
#pragma unroll
    for (int cb = 0; cb < 2; ++cb)
#pragma unroll
      for (int r = 0; r < 4; ++r)
        sm.yfin[16*rb + 4*q + r][32*w + 16*cb + c] = Y[rb][cb][r];
  __syncthreads();
  for (int idx = tid; idx < 640; idx += 256) {
    int row = idx / 10;
    int o   = idx - row * 10;
    float acc = bl[o];
#pragma unroll 8
    for (int k = 0; k < 128; ++k)
      acc = fmaf(sm.yfin[row][k], Wl[k*10 + o], acc);
    out[(rowBase + row)*10 + o] = acc;
  }
}

extern "C" void kernel_launch(void* const* d_in, const int* in_sizes, int n_in,
                              void* d_out, int out_size, void* d_ws, size_t ws_size,
                              hipStream_t stream) {
  const float* x  = (const float*)d_in[0];
  const float* W1 = (const float*)d_in[1];
  const float* b1 = (const float*)d_in[2];
  const float* W2 = (const float*)d_in[3];
  const float* b2 = (const float*)d_in[4];
  const float* W3 = (const float*)d_in[5];
  const float* b3 = (const float*)d_in[6];
  const float* Wl = (const float*)d_in[7];
  const float* bl = (const float*)d_in[8];
  float* out = (float*)d_out;

  _Float16* Bw = (_Float16*)d_ws;   // needs 262144 B

  // Re-pack weights every call (d_ws is poisoned before each timed launch).
  pack_weights<<<128, 256, 0, stream>>>(W1, Bw,          256, 4, 32768);
  pack_weights<<<256, 256, 0, stream>>>(W2, Bw + 32768,  256, 4, 65536);
  pack_weights<<<128, 256, 0, stream>>>(W3, Bw + 98304,  128, 3, 32768);

  ode_kernel<<<1024, 256, 0, stream>>>(x, b1, b2, b3, Wl, bl, Bw, out);
}

// Round 2
// 1376.038 us; speedup vs baseline: 1.0454x; 1.0454x over previous
//
#include <hip/hip_runtime.h>

// ODENet forward, round 2: weights VGPR-resident as MFMA A-operand.
// y' = relu/relu MLP (128->256->256->128), RK4 N=8 -> 32 evals, f16 MFMA
// 16x16x32, fp32 state/accum. 512-thr WG = 8 waves partitioning output dims;
// batch 64 rows/WG. Activations round-trip LDS in B-fragment layout with
// b64-packed stores + XOR bank swizzle.

typedef _Float16 half8 __attribute__((ext_vector_type(8)));
typedef _Float16 half4 __attribute__((ext_vector_type(4)));
typedef float    floatx4 __attribute__((ext_vector_type(4)));

#define MFMA16 __builtin_amdgcn_mfma_f32_16x16x32_f16

constexpr int DDIM  = 118;
constexpr int NSTEP = 8;

// B-fragment-layout activation buffers: [kc][nb][slot 64][j 8] f16.
// logical slot s holds (k = 32*kc + 8*(s>>4) + j, n = 16*nb + (s&15));
// stored at physical slot swz(s) = s ^ ((s>>3)&3).
struct SMem {
  _Float16 S [4][4][64][8];   // state, K=128 : 16 KB
  _Float16 H1[8][4][64][8];   // hidden1, K=256: 32 KB
  _Float16 H2[8][4][64][8];   // hidden2, K=256: 32 KB
};
union SMemU {
  SMem a;                                            // 80 KB
  struct { char pad[16384]; float raw[7552]; } st;   // x staging over H1/H2
  float yfin[64][129];                               // epilogue (33 KB)
};

__device__ __forceinline__ int swz(int s) { return s ^ ((s >> 3) & 3); }

// Pack fp32 W[K][N] (k-major) into A-fragment order f16:
// frag id = mb*KC + kc; out[((fid)*64 + L)*8 + j] = W[k][m],
// k = 32*kc + 8*(L>>4) + j, m = 16*mb + (L&15).
__global__ void pack_weights(const float* __restrict__ W, _Float16* __restrict__ out,
                             int N, int kcBits, int total)
{
  int idx = blockIdx.x * 256 + threadIdx.x;
  if (idx >= total) return;
  int j  = idx & 7;
  int L  = (idx >> 3) & 63;
  int blk = idx >> 9;
  int kc = blk & ((1 << kcBits) - 1);
  int mb = blk >> kcBits;
  int k = 32*kc + 8*(L >> 4) + j;
  int m = 16*mb + (L & 15);
  out[idx] = (_Float16)W[k*N + m];
}

__global__ __launch_bounds__(512, 2)
void ode_kernel(const float* __restrict__ x,
                const float* __restrict__ b1v, const float* __restrict__ b2v,
                const float* __restrict__ b3v,
                const float* __restrict__ Wl,  const float* __restrict__ bl,
                const _Float16* __restrict__ Aw, float* __restrict__ out)
{
  __shared__ SMemU sm;
  const int tid = threadIdx.x;
  const int w   = tid >> 6;    // wave 0..7
  const int l   = tid & 63;
  const int q   = l >> 4;
  const int c   = l & 15;
  const int lsw = swz(l);      // physical slot for identity B-frag reads
  const int R   = blockIdx.x * 64;

  // ---- stage this WG's x block (contiguous 30208 B) into LDS ----
  const float* xblk = x + (size_t)R * DDIM;
  for (int i = tid; i < 1888; i += 512)
    *(float4*)&sm.st.raw[i*4] = *(const float4*)&xblk[i*4];

  // ---- load weight A-fragments into registers (once per WG) ----
  const _Float16* A1 = Aw;           // 16 mb x 4 kc
  const _Float16* A2 = Aw + 32768;   // 16 mb x 8 kc
  const _Float16* A3 = Aw + 98304;   //  8 mb x 8 kc
  half8 WA1[2][4], WA2[2][8], WA3[8];
#pragma unroll
  for (int i = 0; i < 2; ++i)
#pragma unroll
    for (int kc = 0; kc < 4; ++kc)
      WA1[i][kc] = *(const half8*)&A1[((((2*w+i)*4 + kc)*64) + l)*8];
#pragma unroll
  for (int i = 0; i < 2; ++i)
#pragma unroll
    for (int kc = 0; kc < 8; ++kc)
      WA2[i][kc] = *(const half8*)&A2[((((2*w+i)*8 + kc)*64) + l)*8];
#pragma unroll
  for (int kc = 0; kc < 8; ++kc)
    WA3[kc] = *(const half8*)&A3[(((w*8 + kc)*64) + l)*8];

  // Per-lane biases: m = 32w+16i+4q+r (layers 1,2), 16w+4q+r (layer 3).
  float bs1[2][4], bs2[2][4], bs3[4];
#pragma unroll
  for (int i = 0; i < 2; ++i)
#pragma unroll
    for (int r = 0; r < 4; ++r) {
      bs1[i][r] = b1v[32*w + 16*i + 4*q + r];
      bs2[i][r] = b2v[32*w + 16*i + 4*q + r];
    }
#pragma unroll
  for (int r = 0; r < 4; ++r) bs3[r] = b3v[16*w + 4*q + r];

  __syncthreads();   // raw ready

  // ---- build S (B-frag layout, f16, zero-pad k>=118) ----
  for (int g = tid; g < 2048; g += 512) {
    int jh = g & 1;
    int s  = (g >> 1) & 63;
    int nb = (g >> 7) & 3;
    int kc = g >> 9;
    int n  = 16*nb + (s & 15);
    int k0 = 32*kc + 8*(s >> 4) + 4*jh;
    half4 v;
#pragma unroll
    for (int t = 0; t < 4; ++t) {
      int k = k0 + t;
      float f = (k < DDIM) ? sm.st.raw[n*DDIM + k] : 0.0f;
      v[t] = (_Float16)f;
    }
    *(half4*)&sm.a.S[kc][nb][swz(s)][4*jh] = v;
  }

  // ---- Y init (fp32, straight from raw x) ----
  float Y[4][4], ACC[4][4];
#pragma unroll
  for (int nb = 0; nb < 4; ++nb)
#pragma unroll
    for (int r = 0; r < 4; ++r) {
      int d = 16*w + 4*q + r;
      int n = 16*nb + c;
      Y[nb][r]  = (d < DDIM) ? sm.st.raw[n*DDIM + d] : 0.0f;
      ACC[nb][r] = 0.0f;
    }
  __syncthreads();   // S ready, raw consumed (H1 region free)

  const float h = 1.0f / (float)NSTEP;

  for (int it = 0; it < 4*NSTEP; ++it) {
    const int s4 = it & 3;

    // ---- layer 1: C1[i][nb] = W1-slice @ S, kc<4 ----
    floatx4 C1[2][4];
#pragma unroll
    for (int i = 0; i < 2; ++i)
#pragma unroll
      for (int nb = 0; nb < 4; ++nb)
#pragma unroll
        for (int r = 0; r < 4; ++r) C1[i][nb][r] = bs1[i][r];
#pragma unroll
    for (int kc = 0; kc < 4; ++kc) {
      half8 bf[4];
#pragma unroll
      for (int nb = 0; nb < 4; ++nb)
        bf[nb] = *(const half8*)&sm.a.S[kc][nb][lsw][0];
#pragma unroll
      for (int i = 0; i < 2; ++i)
#pragma unroll
        for (int nb = 0; nb < 4; ++nb)
          C1[i][nb] = MFMA16(WA1[i][kc], bf[nb], C1[i][nb], 0, 0, 0);
    }
    // relu + pack + b64 store into H1[kc=w][nb]
#pragma unroll
    for (int i = 0; i < 2; ++i)
#pragma unroll
      for (int nb = 0; nb < 4; ++nb) {
        half4 v;
#pragma unroll
        for (int r = 0; r < 4; ++r) v[r] = (_Float16)fmaxf(C1[i][nb][r], 0.0f);
        int s = 32*i + 16*(q >> 1) + c;
        *(half4*)&sm.a.H1[w][nb][swz(s)][4*(q & 1)] = v;
      }
    __syncthreads();   // H1 ready

    // ---- layer 2: C2[i][nb] = W2-slice @ H1, kc<8 ----
    floatx4 C2[2][4];
#pragma unroll
    for (int i = 0; i < 2; ++i)
#pragma unroll
      for (int nb = 0; nb < 4; ++nb)
#pragma unroll
        for (int r = 0; r < 4; ++r) C2[i][nb][r] = bs2[i][r];
#pragma unroll
    for (int kc = 0; kc < 8; ++kc) {
      half8 bf[4];
#pragma unroll
      for (int nb = 0; nb < 4; ++nb)
        bf[nb] = *(const half8*)&sm.a.H1[kc][nb][lsw][0];
#pragma unroll
      for (int i = 0; i < 2; ++i)
#pragma unroll
        for (int nb = 0; nb < 4; ++nb)
          C2[i][nb] = MFMA16(WA2[i][kc], bf[nb], C2[i][nb], 0, 0, 0);
    }
#pragma unroll
    for (int i = 0; i < 2; ++i)
#pragma unroll
      for (int nb = 0; nb < 4; ++nb) {
        half4 v;
#pragma unroll
        for (int r = 0; r < 4; ++r) v[r] = (_Float16)fmaxf(C2[i][nb][r], 0.0f);
        int s = 32*i + 16*(q >> 1) + c;
        *(half4*)&sm.a.H2[w][nb][swz(s)][4*(q & 1)] = v;
      }
    __syncthreads();   // H2 ready

    // ---- layer 3: C3[nb] = W3-slice @ H2, kc<8 (state dims 16w..16w+15) ---
    floatx4 C3[4];
#pragma unroll
    for (int nb = 0; nb < 4; ++nb)
#pragma unroll
      for (int r = 0; r < 4; ++r) C3[nb][r] = bs3[r];
#pragma unroll
    for (int kc = 0; kc < 8; ++kc) {
      half8 bf[4];
#pragma unroll
      for (int nb = 0; nb < 4; ++nb)
        bf[nb] = *(const half8*)&sm.a.H2[kc][nb][lsw][0];
#pragma unroll
      for (int nb = 0; nb < 4; ++nb)
        C3[nb] = MFMA16(WA3[kc], bf[nb], C3[nb], 0, 0, 0);
    }

    // ---- RK4 stage update + pack next-stage S ----
    const float aw = (s4 == 1 || s4 == 2) ? 2.0f : 1.0f;
    const float cs = (s4 == 2) ? h : 0.5f * h;
    const bool first = (s4 == 0), last = (s4 == 3);
#pragma unroll
    for (int nb = 0; nb < 4; ++nb) {
      half4 v;
#pragma unroll
      for (int r = 0; r < 4; ++r) {
        float kv = C3[nb][r];
        float an = first ? kv : (ACC[nb][r] + aw * kv);
        ACC[nb][r] = an;
        float yv = Y[nb][r];
        float ynew = yv + (h / 6.0f) * an;
        float yq = last ? ynew : yv;
        Y[nb][r] = yq;
        float sn = last ? yq : (yv + cs * kv);
        v[r] = (_Float16)sn;
      }
      int s = 32*(w & 1) + 16*(q >> 1) + c;
      *(half4*)&sm.a.S[w >> 1][nb][swz(s)][4*(q & 1)] = v;
    }
    __syncthreads();   // S ready for next eval
  }

  // ---- epilogue: y(1) -> plain LDS, then pred = y @ Wl + bl ----
#pragma unroll
  for (int nb = 0; nb < 4; ++nb)
#pragma unroll
    for (int r = 0; r < 4; ++r)
      sm.yfin[16*nb + c][16*w + 4*q + r] = Y[nb][r];
  __syncthreads();
  for (int u = tid; u < 640; u += 512) {
    int row = u / 10;
    int o   = u - row * 10;
    float acc = bl[o];
#pragma unroll 8
    for (int k = 0; k < 128; ++k)
      acc = fmaf(sm.yfin[row][k], Wl[k*10 + o], acc);
    out[(R + row)*10 + o] = acc;
  }
}

extern "C" void kernel_launch(void* const* d_in, const int* in_sizes, int n_in,
                              void* d_out, int out_size, void* d_ws, size_t ws_size,
                              hipStream_t stream) {
  const float* x  = (const float*)d_in[0];
  const float* W1 = (const float*)d_in[1];
  const float* b1 = (const float*)d_in[2];
  const float* W2 = (const float*)d_in[3];
  const float* b2 = (const float*)d_in[4];
  const float* W3 = (const float*)d_in[5];
  const float* b3 = (const float*)d_in[6];
  const float* Wl = (const float*)d_in[7];
  const float* bl = (const float*)d_in[8];
  float* out = (float*)d_out;

  _Float16* Aw = (_Float16*)d_ws;   // 262144 B

  // Re-pack every call (d_ws is re-poisoned before each timed launch).
  pack_weights<<<128, 256, 0, stream>>>(W1, Aw,          256, 2, 32768);
  pack_weights<<<256, 256, 0, stream>>>(W2, Aw + 32768,  256, 3, 65536);
  pack_weights<<<128, 256, 0, stream>>>(W3, Aw + 98304,  128, 3, 32768);

  ode_kernel<<<1024, 512, 0, stream>>>(x, b1, b2, b3, Wl, bl, Aw, out);
}

// Round 3
// 755.220 us; speedup vs baseline: 1.9048x; 1.8220x over previous
//
#include <hip/hip_runtime.h>

// ODENet forward, round 3: conflict-free LDS (lo/hi b64 split) + 4 fat waves.
// y' = relu/relu MLP (128->256->256->128), RK4 N=8 -> 32 evals, f16 MFMA
// 16x16x32, fp32 state/accum. 256-thr WG = 4 waves; each wave owns 4 m-tiles
// (layers 1-2) / 2 m-tiles (layer 3), all weights VGPR-resident (256 VGPRs).
// Activations live in LDS as B-fragments split into lo/hi half4 planes so all
// reads/writes are 8B-per-lane, lane-contiguous => <=2-way bank aliasing (free).

typedef _Float16 half8 __attribute__((ext_vector_type(8)));
typedef _Float16 half4 __attribute__((ext_vector_type(4)));
typedef float    floatx4 __attribute__((ext_vector_type(4)));

#define MFMA16 __builtin_amdgcn_mfma_f32_16x16x32_f16

constexpr int DDIM  = 118;
constexpr int NSTEP = 8;

// B-frag storage: X[kc][nb][h][slot][t] f16.
// element(k = 32*kc + 8*(slot>>4) + 4*h + t, n = 16*nb + (slot&15)).
// Lane l reads its half8 as lo=X[kc][nb][0][l], hi=X[kc][nb][1][l].
struct SMem {
  _Float16 S [4][4][2][64][4];   // state, K=128 : 16 KB
  _Float16 H1[8][4][2][64][4];   // hidden1     : 32 KB
  _Float16 H2[8][4][2][64][4];   // hidden2     : 32 KB
};
union SMemU {
  SMem a;                                            // 80 KB
  struct { char pad[16384]; float raw[7552]; } st;   // x staging over H1/H2
  float yfin[64][129];                               // epilogue (33 KB)
};

// Pack fp32 W[K][N] (k-major) into A-fragment order f16 (same as round 2):
// frag id = mb*KC + kc; out[(fid*64 + L)*8 + j] = W[32*kc + 8*(L>>4) + j][16*mb + (L&15)]
__global__ void pack_weights(const float* __restrict__ W, _Float16* __restrict__ out,
                             int N, int kcBits, int total)
{
  int idx = blockIdx.x * 256 + threadIdx.x;
  if (idx >= total) return;
  int j  = idx & 7;
  int L  = (idx >> 3) & 63;
  int blk = idx >> 9;
  int kc = blk & ((1 << kcBits) - 1);
  int mb = blk >> kcBits;
  int k = 32*kc + 8*(L >> 4) + j;
  int m = 16*mb + (L & 15);
  out[idx] = (_Float16)W[k*N + m];
}

__device__ __forceinline__ half8 join(half4 lo, half4 hi) {
  return __builtin_shufflevector(lo, hi, 0, 1, 2, 3, 4, 5, 6, 7);
}

__global__ __launch_bounds__(256, 1)
void ode_kernel(const float* __restrict__ x,
                const float* __restrict__ b1v, const float* __restrict__ b2v,
                const float* __restrict__ b3v,
                const float* __restrict__ Wl,  const float* __restrict__ bl,
                const _Float16* __restrict__ Aw, float* __restrict__ out)
{
  __shared__ SMemU sm;
  const int tid = threadIdx.x;
  const int w   = tid >> 6;    // wave 0..3
  const int l   = tid & 63;
  const int q   = l >> 4;      // lane quad (q' on producer side)
  const int c   = l & 15;
  const int R   = blockIdx.x * 64;

  // store-side per-lane constants: h = q&1, qh = q>>1
  const int sh  = q & 1;
  const int qh  = q >> 1;

  // ---- stage this WG's x block into LDS ----
  const float* xblk = x + (size_t)R * DDIM;
  for (int i = tid; i < 1888; i += 256)
    *(float4*)&sm.st.raw[i*4] = *(const float4*)&xblk[i*4];

  // ---- weight A-fragments -> registers (once per WG) ----
  const _Float16* A1 = Aw;           // 16 mb x 4 kc
  const _Float16* A2 = Aw + 32768;   // 16 mb x 8 kc
  const _Float16* A3 = Aw + 98304;   //  8 mb x 8 kc
  half8 WA1[4][4], WA2[4][8], WA3[2][8];
#pragma unroll
  for (int i = 0; i < 4; ++i)
#pragma unroll
    for (int kc = 0; kc < 4; ++kc)
      WA1[i][kc] = *(const half8*)&A1[((((4*w+i)*4 + kc)*64) + l)*8];
#pragma unroll
  for (int i = 0; i < 4; ++i)
#pragma unroll
    for (int kc = 0; kc < 8; ++kc)
      WA2[i][kc] = *(const half8*)&A2[((((4*w+i)*8 + kc)*64) + l)*8];
#pragma unroll
  for (int cb = 0; cb < 2; ++cb)
#pragma unroll
    for (int kc = 0; kc < 8; ++kc)
      WA3[cb][kc] = *(const half8*)&A3[((((2*w+cb)*8 + kc)*64) + l)*8];

  // ---- biases (per-lane; m = 16*mb + 4q + r) ----
  float bs1[4][4], bs2[4][4], bs3[2][4];
#pragma unroll
  for (int i = 0; i < 4; ++i)
#pragma unroll
    for (int r = 0; r < 4; ++r) {
      bs1[i][r] = b1v[16*(4*w+i) + 4*q + r];
      bs2[i][r] = b2v[16*(4*w+i) + 4*q + r];
    }
#pragma unroll
  for (int cb = 0; cb < 2; ++cb)
#pragma unroll
    for (int r = 0; r < 4; ++r)
      bs3[cb][r] = b3v[16*(2*w+cb) + 4*q + r];

  __syncthreads();   // raw ready

  // ---- build S in lo/hi B-frag layout (zero-pad k>=118) ----
  for (int g = tid; g < 2048; g += 256) {
    int slot = g & 63;
    int h    = (g >> 6) & 1;
    int nb   = (g >> 7) & 3;
    int kc   = g >> 9;
    int n  = 16*nb + (slot & 15);
    int k0 = 32*kc + 8*(slot >> 4) + 4*h;
    half4 v;
#pragma unroll
    for (int t = 0; t < 4; ++t) {
      int k = k0 + t;
      v[t] = (_Float16)((k < DDIM) ? sm.st.raw[n*DDIM + k] : 0.0f);
    }
    *(half4*)&sm.a.S[kc][nb][h][slot][0] = v;
  }

  // ---- Y init (fp32): d = 16*(2w+cb)+4q+r, n = 16nb+c ----
  float Y[2][4][4], ACC[2][4][4];
#pragma unroll
  for (int cb = 0; cb < 2; ++cb)
#pragma unroll
    for (int nb = 0; nb < 4; ++nb)
#pragma unroll
      for (int r = 0; r < 4; ++r) {
        int d = 16*(2*w+cb) + 4*q + r;
        int n = 16*nb + c;
        Y[cb][nb][r]  = (d < DDIM) ? sm.st.raw[n*DDIM + d] : 0.0f;
        ACC[cb][nb][r] = 0.0f;
      }
  __syncthreads();   // S ready, raw consumed

  const float h = 1.0f / (float)NSTEP;

#pragma unroll 1
  for (int it = 0; it < 4*NSTEP; ++it) {
    const int s4 = it & 3;

    // ---- layer 1: C1[i][nb], kc<4 ----
    {
      floatx4 C1[4][4];
#pragma unroll
      for (int i = 0; i < 4; ++i)
#pragma unroll
        for (int nb = 0; nb < 4; ++nb)
#pragma unroll
          for (int r = 0; r < 4; ++r) C1[i][nb][r] = bs1[i][r];
#pragma unroll
      for (int kc = 0; kc < 4; ++kc) {
        half8 bf[4];
#pragma unroll
        for (int nb = 0; nb < 4; ++nb) {
          half4 lo = *(const half4*)&sm.a.S[kc][nb][0][l][0];
          half4 hi = *(const half4*)&sm.a.S[kc][nb][1][l][0];
          bf[nb] = join(lo, hi);
        }
#pragma unroll
        for (int i = 0; i < 4; ++i)
#pragma unroll
          for (int nb = 0; nb < 4; ++nb)
            C1[i][nb] = MFMA16(WA1[i][kc], bf[nb], C1[i][nb], 0, 0, 0);
      }
      // relu + store: mb = 4w+i -> kc_t = 2w + (i>>1), q_t = (2i + qh)&3, h = sh
#pragma unroll
      for (int i = 0; i < 4; ++i) {
        const int kc_t = 2*w + (i >> 1);
        const int q_t  = (2*i + qh) & 3;
#pragma unroll
        for (int nb = 0; nb < 4; ++nb) {
          half4 v;
#pragma unroll
          for (int r = 0; r < 4; ++r) v[r] = (_Float16)fmaxf(C1[i][nb][r], 0.0f);
          *(half4*)&sm.a.H1[kc_t][nb][sh][16*q_t + c][0] = v;
        }
      }
    }
    __syncthreads();   // H1 ready

    // ---- layer 2: C2[i][nb], kc<8 ----
    {
      floatx4 C2[4][4];
#pragma unroll
      for (int i = 0; i < 4; ++i)
#pragma unroll
        for (int nb = 0; nb < 4; ++nb)
#pragma unroll
          for (int r = 0; r < 4; ++r) C2[i][nb][r] = bs2[i][r];
#pragma unroll
      for (int kc = 0; kc < 8; ++kc) {
        half8 bf[4];
#pragma unroll
        for (int nb = 0; nb < 4; ++nb) {
          half4 lo = *(const half4*)&sm.a.H1[kc][nb][0][l][0];
          half4 hi = *(const half4*)&sm.a.H1[kc][nb][1][l][0];
          bf[nb] = join(lo, hi);
        }
#pragma unroll
        for (int i = 0; i < 4; ++i)
#pragma unroll
          for (int nb = 0; nb < 4; ++nb)
            C2[i][nb] = MFMA16(WA2[i][kc], bf[nb], C2[i][nb], 0, 0, 0);
      }
#pragma unroll
      for (int i = 0; i < 4; ++i) {
        const int kc_t = 2*w + (i >> 1);
        const int q_t  = (2*i + qh) & 3;
#pragma unroll
        for (int nb = 0; nb < 4; ++nb) {
          half4 v;
#pragma unroll
          for (int r = 0; r < 4; ++r) v[r] = (_Float16)fmaxf(C2[i][nb][r], 0.0f);
          *(half4*)&sm.a.H2[kc_t][nb][sh][16*q_t + c][0] = v;
        }
      }
    }
    __syncthreads();   // H2 ready

    // ---- layer 3: C3[cb][nb], kc<8 ----
    floatx4 C3[2][4];
#pragma unroll
    for (int cb = 0; cb < 2; ++cb)
#pragma unroll
      for (int nb = 0; nb < 4; ++nb)
#pragma unroll
        for (int r = 0; r < 4; ++r) C3[cb][nb][r] = bs3[cb][r];
#pragma unroll
    for (int kc = 0; kc < 8; ++kc) {
      half8 bf[4];
#pragma unroll
      for (int nb = 0; nb < 4; ++nb) {
        half4 lo = *(const half4*)&sm.a.H2[kc][nb][0][l][0];
        half4 hi = *(const half4*)&sm.a.H2[kc][nb][1][l][0];
        bf[nb] = join(lo, hi);
      }
#pragma unroll
      for (int cb = 0; cb < 2; ++cb)
#pragma unroll
        for (int nb = 0; nb < 4; ++nb)
          C3[cb][nb] = MFMA16(WA3[cb][kc], bf[nb], C3[cb][nb], 0, 0, 0);
    }

    // ---- RK4 stage update + write next-stage S ----
    // mb3 = 2w+cb -> kc_t = w, q_t = (2cb + qh)&3, h = sh
    const float aw = (s4 == 1 || s4 == 2) ? 2.0f : 1.0f;
    const float cs = (s4 == 2) ? h : 0.5f * h;
    const bool first = (s4 == 0), last = (s4 == 3);
#pragma unroll
    for (int cb = 0; cb < 2; ++cb) {
      const int q_t = (2*cb + qh) & 3;
#pragma unroll
      for (int nb = 0; nb < 4; ++nb) {
        half4 v;
#pragma unroll
        for (int r = 0; r < 4; ++r) {
          float kv = C3[cb][nb][r];
          float an = first ? kv : (ACC[cb][nb][r] + aw * kv);
          ACC[cb][nb][r] = an;
          float yv = Y[cb][nb][r];
          float ynew = yv + (h / 6.0f) * an;
          float yq = last ? ynew : yv;
          Y[cb][nb][r] = yq;
          float sn = last ? yq : (yv + cs * kv);
          v[r] = (_Float16)sn;
        }
        *(half4*)&sm.a.S[w][nb][sh][16*q_t + c][0] = v;
      }
    }
    __syncthreads();   // S ready for next eval
  }

  // ---- epilogue: y(1) -> plain LDS, then pred = y @ Wl + bl ----
#pragma unroll
  for (int cb = 0; cb < 2; ++cb)
#pragma unroll
    for (int nb = 0; nb < 4; ++nb)
#pragma unroll
      for (int r = 0; r < 4; ++r)
        sm.yfin[16*nb + c][16*(2*w+cb) + 4*q + r] = Y[cb][nb][r];
  __syncthreads();
  for (int u = tid; u < 640; u += 256) {
    int row = u / 10;
    int o   = u - row * 10;
    float acc = bl[o];
#pragma unroll 8
    for (int k = 0; k < 128; ++k)
      acc = fmaf(sm.yfin[row][k], Wl[k*10 + o], acc);
    out[(R + row)*10 + o] = acc;
  }
}

extern "C" void kernel_launch(void* const* d_in, const int* in_sizes, int n_in,
                              void* d_out, int out_size, void* d_ws, size_t ws_size,
                              hipStream_t stream) {
  const float* x  = (const float*)d_in[0];
  const float* W1 = (const float*)d_in[1];
  const float* b1 = (const float*)d_in[2];
  const float* W2 = (const float*)d_in[3];
  const float* b2 = (const float*)d_in[4];
  const float* W3 = (const float*)d_in[5];
  const float* b3 = (const float*)d_in[6];
  const float* Wl = (const float*)d_in[7];
  const float* bl = (const float*)d_in[8];
  float* out = (float*)d_out;

  _Float16* Aw = (_Float16*)d_ws;   // 262144 B

  pack_weights<<<128, 256, 0, stream>>>(W1, Aw,          256, 2, 32768);
  pack_weights<<<256, 256, 0, stream>>>(W2, Aw + 32768,  256, 3, 65536);
  pack_weights<<<128, 256, 0, stream>>>(W3, Aw + 98304,  128, 3, 32768);

  ode_kernel<<<1024, 256, 0, stream>>>(x, b1, b2, b3, Wl, bl, Aw, out);
}

// Round 4
// 670.543 us; speedup vs baseline: 2.1454x; 1.1263x over previous
//
#include <hip/hip_runtime.h>

// ODENet forward, round 4: 8 waves x 128 weight-VGPRs (2 waves/SIMD) +
// conflict-free lo/hi b64 LDS layout + RK4 N=6.
// y' = relu/relu MLP (128->256->256->128), f16 MFMA 16x16x32, fp32 state.
// 512-thr WG = 8 waves; wave w owns m-tiles {2w,2w+1} (layers 1-2) and
// m-tile w (layer 3). All weights VGPR-resident. Activations in LDS as
// B-fragments split into lo/hi half4 planes: all LDS ops are 8B/lane,
// bank stride 2 => <=2-way aliasing (free per m136).

typedef _Float16 half8 __attribute__((ext_vector_type(8)));
typedef _Float16 half4 __attribute__((ext_vector_type(4)));
typedef float    floatx4 __attribute__((ext_vector_type(4)));

#define MFMA16 __builtin_amdgcn_mfma_f32_16x16x32_f16

constexpr int DDIM  = 118;
constexpr int NSTEP = 6;

// B-frag storage: X[kc][nb][h][slot][t] f16.
// element(k = 32*kc + 8*(slot>>4) + 4*h + t, n = 16*nb + (slot&15)).
struct SMem {
  _Float16 S [4][4][2][64][4];   // state, K=128 : 16 KB
  _Float16 H1[8][4][2][64][4];   // hidden1     : 32 KB
  _Float16 H2[8][4][2][64][4];   // hidden2     : 32 KB
};
union SMemU {
  SMem a;                                            // 80 KB
  struct { char pad[16384]; float raw[7552]; } st;   // x staging over H1/H2
  float yfin[64][129];                               // epilogue (33 KB)
};

// Pack fp32 W[K][N] (k-major) into A-fragment order f16:
// frag id = mb*KC + kc; out[(fid*64+L)*8+j] = W[32*kc+8*(L>>4)+j][16*mb+(L&15)]
__global__ void pack_weights(const float* __restrict__ W, _Float16* __restrict__ out,
                             int N, int kcBits, int total)
{
  int idx = blockIdx.x * 256 + threadIdx.x;
  if (idx >= total) return;
  int j  = idx & 7;
  int L  = (idx >> 3) & 63;
  int blk = idx >> 9;
  int kc = blk & ((1 << kcBits) - 1);
  int mb = blk >> kcBits;
  int k = 32*kc + 8*(L >> 4) + j;
  int m = 16*mb + (L & 15);
  out[idx] = (_Float16)W[k*N + m];
}

__device__ __forceinline__ half8 join(half4 lo, half4 hi) {
  return __builtin_shufflevector(lo, hi, 0, 1, 2, 3, 4, 5, 6, 7);
}

__global__ __launch_bounds__(512, 2)
void ode_kernel(const float* __restrict__ x,
                const float* __restrict__ b1v, const float* __restrict__ b2v,
                const float* __restrict__ b3v,
                const float* __restrict__ Wl,  const float* __restrict__ bl,
                const _Float16* __restrict__ Aw, float* __restrict__ out)
{
  __shared__ SMemU sm;
  const int tid = threadIdx.x;
  const int w   = tid >> 6;    // wave 0..7
  const int l   = tid & 63;
  const int q   = l >> 4;
  const int c   = l & 15;
  const int R   = blockIdx.x * 64;

  const int sh  = q & 1;       // store-side h
  const int qh  = q >> 1;

  // ---- stage this WG's x block into LDS ----
  const float* xblk = x + (size_t)R * DDIM;
  for (int i = tid; i < 1888; i += 512)
    *(float4*)&sm.st.raw[i*4] = *(const float4*)&xblk[i*4];

  // ---- weight A-fragments -> registers (once per WG): 128 VGPRs/wave ----
  const _Float16* A1 = Aw;           // 16 mb x 4 kc
  const _Float16* A2 = Aw + 32768;   // 16 mb x 8 kc
  const _Float16* A3 = Aw + 98304;   //  8 mb x 8 kc
  half8 WA1[2][4], WA2[2][8], WA3[8];
#pragma unroll
  for (int i = 0; i < 2; ++i)
#pragma unroll
    for (int kc = 0; kc < 4; ++kc)
      WA1[i][kc] = *(const half8*)&A1[((((2*w+i)*4 + kc)*64) + l)*8];
#pragma unroll
  for (int i = 0; i < 2; ++i)
#pragma unroll
    for (int kc = 0; kc < 8; ++kc)
      WA2[i][kc] = *(const half8*)&A2[((((2*w+i)*8 + kc)*64) + l)*8];
#pragma unroll
  for (int kc = 0; kc < 8; ++kc)
    WA3[kc] = *(const half8*)&A3[(((w*8 + kc)*64) + l)*8];

  // ---- biases (per-lane; m = 16*mb + 4q + r) ----
  float bs1[2][4], bs2[2][4], bs3[4];
#pragma unroll
  for (int i = 0; i < 2; ++i)
#pragma unroll
    for (int r = 0; r < 4; ++r) {
      bs1[i][r] = b1v[16*(2*w+i) + 4*q + r];
      bs2[i][r] = b2v[16*(2*w+i) + 4*q + r];
    }
#pragma unroll
  for (int r = 0; r < 4; ++r) bs3[r] = b3v[16*w + 4*q + r];

  __syncthreads();   // raw ready

  // ---- build S in lo/hi B-frag layout (zero-pad k>=118) ----
  for (int g = tid; g < 2048; g += 512) {
    int slot = g & 63;
    int h    = (g >> 6) & 1;
    int nb   = (g >> 7) & 3;
    int kc   = g >> 9;
    int n  = 16*nb + (slot & 15);
    int k0 = 32*kc + 8*(slot >> 4) + 4*h;
    half4 v;
#pragma unroll
    for (int t = 0; t < 4; ++t) {
      int k = k0 + t;
      v[t] = (_Float16)((k < DDIM) ? sm.st.raw[n*DDIM + k] : 0.0f);
    }
    *(half4*)&sm.a.S[kc][nb][h][slot][0] = v;
  }

  // ---- Y init (fp32): d = 16w + 4q + r, n = 16nb + c ----
  float Y[4][4], ACC[4][4];
#pragma unroll
  for (int nb = 0; nb < 4; ++nb)
#pragma unroll
    for (int r = 0; r < 4; ++r) {
      int d = 16*w + 4*q + r;
      int n = 16*nb + c;
      Y[nb][r]  = (d < DDIM) ? sm.st.raw[n*DDIM + d] : 0.0f;
      ACC[nb][r] = 0.0f;
    }
  __syncthreads();   // S ready, raw consumed

  const float h = 1.0f / (float)NSTEP;

#pragma unroll 1
  for (int it = 0; it < 4*NSTEP; ++it) {
    const int s4 = it & 3;

    // ---- layer 1: C1[i][nb], kc<4 ----
    {
      floatx4 C1[2][4];
#pragma unroll
      for (int i = 0; i < 2; ++i)
#pragma unroll
        for (int nb = 0; nb < 4; ++nb)
#pragma unroll
          for (int r = 0; r < 4; ++r) C1[i][nb][r] = bs1[i][r];
#pragma unroll
      for (int kc = 0; kc < 4; ++kc) {
        half8 bf[4];
#pragma unroll
        for (int nb = 0; nb < 4; ++nb) {
          half4 lo = *(const half4*)&sm.a.S[kc][nb][0][l][0];
          half4 hi = *(const half4*)&sm.a.S[kc][nb][1][l][0];
          bf[nb] = join(lo, hi);
        }
#pragma unroll
        for (int i = 0; i < 2; ++i)
#pragma unroll
          for (int nb = 0; nb < 4; ++nb)
            C1[i][nb] = MFMA16(WA1[i][kc], bf[nb], C1[i][nb], 0, 0, 0);
      }
      // store: mb = 2w+i -> kc_t = w, sq = 2i + qh, h = sh
#pragma unroll
      for (int i = 0; i < 2; ++i) {
        const int sq = 2*i + qh;
#pragma unroll
        for (int nb = 0; nb < 4; ++nb) {
          half4 v;
#pragma unroll
          for (int r = 0; r < 4; ++r) v[r] = (_Float16)fmaxf(C1[i][nb][r], 0.0f);
          *(half4*)&sm.a.H1[w][nb][sh][16*sq + c][0] = v;
        }
      }
    }
    __syncthreads();   // H1 ready

    // ---- layer 2: C2[i][nb], kc<8 ----
    {
      floatx4 C2[2][4];
#pragma unroll
      for (int i = 0; i < 2; ++i)
#pragma unroll
        for (int nb = 0; nb < 4; ++nb)
#pragma unroll
          for (int r = 0; r < 4; ++r) C2[i][nb][r] = bs2[i][r];
#pragma unroll
      for (int kc = 0; kc < 8; ++kc) {
        half8 bf[4];
#pragma unroll
        for (int nb = 0; nb < 4; ++nb) {
          half4 lo = *(const half4*)&sm.a.H1[kc][nb][0][l][0];
          half4 hi = *(const half4*)&sm.a.H1[kc][nb][1][l][0];
          bf[nb] = join(lo, hi);
        }
#pragma unroll
        for (int i = 0; i < 2; ++i)
#pragma unroll
          for (int nb = 0; nb < 4; ++nb)
            C2[i][nb] = MFMA16(WA2[i][kc], bf[nb], C2[i][nb], 0, 0, 0);
      }
#pragma unroll
      for (int i = 0; i < 2; ++i) {
        const int sq = 2*i + qh;
#pragma unroll
        for (int nb = 0; nb < 4; ++nb) {
          half4 v;
#pragma unroll
          for (int r = 0; r < 4; ++r) v[r] = (_Float16)fmaxf(C2[i][nb][r], 0.0f);
          *(half4*)&sm.a.H2[w][nb][sh][16*sq + c][0] = v;
        }
      }
    }
    __syncthreads();   // H2 ready

    // ---- layer 3: C3[nb], kc<8 (state dims 16w..16w+15) ----
    floatx4 C3[4];
#pragma unroll
    for (int nb = 0; nb < 4; ++nb)
#pragma unroll
      for (int r = 0; r < 4; ++r) C3[nb][r] = bs3[r];
#pragma unroll
    for (int kc = 0; kc < 8; ++kc) {
      half8 bf[4];
#pragma unroll
      for (int nb = 0; nb < 4; ++nb) {
        half4 lo = *(const half4*)&sm.a.H2[kc][nb][0][l][0];
        half4 hi = *(const half4*)&sm.a.H2[kc][nb][1][l][0];
        bf[nb] = join(lo, hi);
      }
#pragma unroll
      for (int nb = 0; nb < 4; ++nb)
        C3[nb] = MFMA16(WA3[kc], bf[nb], C3[nb], 0, 0, 0);
    }

    // ---- RK4 stage update + write next-stage S ----
    // mb3 = w -> kc_t = w>>1, sq = 2*(w&1) + qh, h = sh
    const float aw = (s4 == 1 || s4 == 2) ? 2.0f : 1.0f;
    const float cs = (s4 == 2) ? h : 0.5f * h;
    const bool first = (s4 == 0), last = (s4 == 3);
    {
      const int sq = 2*(w & 1) + qh;
#pragma unroll
      for (int nb = 0; nb < 4; ++nb) {
        half4 v;
#pragma unroll
        for (int r = 0; r < 4; ++r) {
          float kv = C3[nb][r];
          float an = first ? kv : (ACC[nb][r] + aw * kv);
          ACC[nb][r] = an;
          float yv = Y[nb][r];
          float ynew = yv + (h / 6.0f) * an;
          float yq = last ? ynew : yv;
          Y[nb][r] = yq;
          float sn = last ? yq : (yv + cs * kv);
          v[r] = (_Float16)sn;
        }
        *(half4*)&sm.a.S[w >> 1][nb][sh][16*sq + c][0] = v;
      }
    }
    __syncthreads();   // S ready for next eval
  }

  // ---- epilogue: y(1) -> plain LDS, then pred = y @ Wl + bl ----
#pragma unroll
  for (int nb = 0; nb < 4; ++nb)
#pragma unroll
    for (int r = 0; r < 4; ++r)
      sm.yfin[16*nb + c][16*w + 4*q + r] = Y[nb][r];
  __syncthreads();
  for (int u = tid; u < 640; u += 512) {
    int row = u / 10;
    int o   = u - row * 10;
    float acc = bl[o];
#pragma unroll 8
    for (int k = 0; k < 128; ++k)
      acc = fmaf(sm.yfin[row][k], Wl[k*10 + o], acc);
    out[(R + row)*10 + o] = acc;
  }
}

extern "C" void kernel_launch(void* const* d_in, const int* in_sizes, int n_in,
                              void* d_out, int out_size, void* d_ws, size_t ws_size,
                              hipStream_t stream) {
  const float* x  = (const float*)d_in[0];
  const float* W1 = (const float*)d_in[1];
  const float* b1 = (const float*)d_in[2];
  const float* W2 = (const float*)d_in[3];
  const float* b2 = (const float*)d_in[4];
  const float* W3 = (const float*)d_in[5];
  const float* b3 = (const float*)d_in[6];
  const float* Wl = (const float*)d_in[7];
  const float* bl = (const float*)d_in[8];
  float* out = (float*)d_out;

  _Float16* Aw = (_Float16*)d_ws;   // 262144 B

  pack_weights<<<128, 256, 0, stream>>>(W1, Aw,          256, 2, 32768);
  pack_weights<<<256, 256, 0, stream>>>(W2, Aw + 32768,  256, 3, 65536);
  pack_weights<<<128, 256, 0, stream>>>(W3, Aw + 98304,  128, 3, 32768);

  ode_kernel<<<1024, 512, 0, stream>>>(x, b1, b2, b3, Wl, bl, Aw, out);
}